// Round 1
// baseline (519.831 us; speedup 1.0000x reference)
//
#include <hip/hip_runtime.h>
#include <math.h>

typedef short s16x4 __attribute__((ext_vector_type(4)));
typedef short s16x8 __attribute__((ext_vector_type(8)));
typedef float f32x4 __attribute__((ext_vector_type(4)));

#define NSAMP   524288
#define NFRAMES 1025
#define NFREQ   513
#define NROWS   1026
#define FL      1024
#define BM      128
#define BN      128
#define BK      64
#define LDK     72   // BK + 8 bf16 pad: 144B row stride -> 4-bank shift/row, conflict-free b128 reads

__device__ __forceinline__ unsigned short f2bf(float f) {
    unsigned u = __float_as_uint(f);
    u += 0x7fffu + ((u >> 16) & 1u);   // round-to-nearest-even
    return (unsigned short)(u >> 16);
}

__device__ __forceinline__ s16x4 cvt4(f32x4 f) {
    s16x4 r;
    r[0] = (short)f2bf(f[0]);
    r[1] = (short)f2bf(f[1]);
    r[2] = (short)f2bf(f[2]);
    r[3] = (short)f2bf(f[3]);
    return r;
}

// GEMM row m -> basis row (m>>1) + (m&1)*513  (interleaved real/imag so each
// lane's 4 acc regs hold (re,im) pairs of two adjacent freqs -> fused sqrt).
__global__ __launch_bounds__(256, 2) void stft_mfma_kernel(
    const float* __restrict__ x, const float* __restrict__ basis,
    float* __restrict__ out)
{
    __shared__ short Asl[BM][LDK];
    __shared__ short Bsl[BN][LDK];

    const int tid = threadIdx.x;
    const int mt  = blockIdx.x;   // 0..8  (freq-pair tiles, 9*128 = 1152 >= 1026)
    const int tt  = blockIdx.y;   // 0..8  (frame tiles,     9*128 = 1152 >= 1025)
    const int b   = blockIdx.z;   // 0..31

    const float* __restrict__ xb = x + (size_t)b * NSAMP;

    const int wave = tid >> 6, lane = tid & 63;
    const int wm = wave >> 1, wn = wave & 1;
    const int lm = lane & 15, quad = lane >> 4;

    f32x4 acc[4][4];
#pragma unroll
    for (int i = 0; i < 4; ++i)
#pragma unroll
        for (int j = 0; j < 4; ++j)
            acc[i][j] = (f32x4)(0.f);

    const int c4 = (tid & 15) * 4;  // column offset (elements) for staging
    const int r0 = tid >> 4;        // row 0..15, stepped by 16

    for (int k0 = 0; k0 < FL; k0 += BK) {
        __syncthreads();
        // ---- stage A: basis tile (fp32 -> bf16), interleaved row mapping ----
#pragma unroll
        for (int p = 0; p < 8; ++p) {
            int r  = r0 + p * 16;
            int mg = mt * BM + r;
            s16x4 sv = (s16x4)(short)0;
            if (mg < NROWS) {
                int br = (mg >> 1) + (mg & 1) * NFREQ;
                f32x4 f = *reinterpret_cast<const f32x4*>(basis + (size_t)br * FL + k0 + c4);
                sv = cvt4(f);
            }
            *reinterpret_cast<s16x4*>(&Asl[r][c4]) = sv;
        }
        // ---- stage B: frame tile with reflect padding (fp32 -> bf16) ----
#pragma unroll
        for (int p = 0; p < 8; ++p) {
            int r = r0 + p * 16;
            int t = tt * BN + r;
            int s = t * 512 + k0 + c4 - 512;   // sample index into un-padded signal
            f32x4 f;
            if (s >= 0 && s <= NSAMP - 4) {
                f = *reinterpret_cast<const f32x4*>(xb + s);   // 16B-aligned (s % 4 == 0)
            } else {
#pragma unroll
                for (int e = 0; e < 4; ++e) {
                    int ss = s + e;
                    if (ss < 0) ss = -ss;                       // reflect left
                    if (ss >= NSAMP) ss = 2 * (NSAMP - 1) - ss; // reflect right
                    f[e] = xb[ss];
                }
            }
            *reinterpret_cast<s16x4*>(&Bsl[r][c4]) = cvt4(f);
        }
        __syncthreads();
        // ---- MFMA: 2 k-steps of 32, 4x4 tiles of 16x16x32 per wave ----
#pragma unroll
        for (int kk = 0; kk < BK; kk += 32) {
            s16x8 af[4], bfv[4];
#pragma unroll
            for (int i = 0; i < 4; ++i)
                af[i] = *reinterpret_cast<const s16x8*>(&Asl[wm * 64 + i * 16 + lm][kk + quad * 8]);
#pragma unroll
            for (int j = 0; j < 4; ++j)
                bfv[j] = *reinterpret_cast<const s16x8*>(&Bsl[wn * 64 + j * 16 + lm][kk + quad * 8]);
#pragma unroll
            for (int i = 0; i < 4; ++i)
#pragma unroll
                for (int j = 0; j < 4; ++j)
                    acc[i][j] = __builtin_amdgcn_mfma_f32_16x16x32_bf16(
                        af[i], bfv[j], acc[i][j], 0, 0, 0);
        }
    }

    // ---- epilogue: magnitude in-register, coalesced store along t ----
    const size_t ob = (size_t)b * NFREQ * NFRAMES;
#pragma unroll
    for (int i = 0; i < 4; ++i) {
        int mrow = mt * BM + wm * 64 + i * 16 + quad * 4;  // even (multiple of 4)
        int g0 = mrow >> 1;                                // regs 0,1 = (re,im) of g0; 2,3 of g0+1
#pragma unroll
        for (int j = 0; j < 4; ++j) {
            int t = tt * BN + wn * 64 + j * 16 + lm;
            if (t >= NFRAMES) continue;
            f32x4 v = acc[i][j];
            float m0 = sqrtf(v[0] * v[0] + v[1] * v[1]);
            float m1 = sqrtf(v[2] * v[2] + v[3] * v[3]);
            if (g0 < NFREQ)     out[ob + (size_t)g0 * NFRAMES + t] = m0;
            if (g0 + 1 < NFREQ) out[ob + (size_t)(g0 + 1) * NFRAMES + t] = m1;
        }
    }
}

extern "C" void kernel_launch(void* const* d_in, const int* in_sizes, int n_in,
                              void* d_out, int out_size, void* d_ws, size_t ws_size,
                              hipStream_t stream) {
    const float* x     = (const float*)d_in[0];   // (32, 524288) fp32
    const float* basis = (const float*)d_in[1];   // (1026, 1024) fp32
    float* out = (float*)d_out;                   // (32, 513, 1025) fp32
    dim3 grid(9, 9, 32);
    stft_mfma_kernel<<<grid, 256, 0, stream>>>(x, basis, out);
}

// Round 2
// 220.404 us; speedup vs baseline: 2.3585x; 2.3585x over previous
//
#include <hip/hip_runtime.h>
#include <math.h>

typedef short s16x4 __attribute__((ext_vector_type(4)));
typedef short s16x8 __attribute__((ext_vector_type(8)));
typedef float f32x4 __attribute__((ext_vector_type(4)));

#define NSAMP   524288
#define NFRAMES 1025
#define NFREQ   513
#define NROWS   1026
#define MPAD    1152            // 9*128, A rows padded with zeros
#define FL      1024
#define PADLEN  525312          // NSAMP + 1024 (reflect-padded length)
#define BM      128
#define BN      128
#define BK      64

__device__ __forceinline__ unsigned short f2bf(float f) {
    unsigned u = __float_as_uint(f);
    u += 0x7fffu + ((u >> 16) & 1u);   // round-to-nearest-even
    return (unsigned short)(u >> 16);
}

// ---- pre-pass 1: basis fp32 -> bf16, interleaved rows (m -> (m>>1)+(m&1)*513),
// ---- rows 1026..1151 zeroed. 1152*1024 elems, 8 per thread.
__global__ __launch_bounds__(256) void cvt_basis_kernel(
    const float* __restrict__ basis, unsigned short* __restrict__ Abf)
{
    int gid = blockIdx.x * 256 + threadIdx.x;
    int m = gid >> 7;              // 128 chunks of 8 per row
    int c = (gid & 127) * 8;
    s16x8 v = (s16x8)(short)0;
    if (m < NROWS) {
        int br = (m >> 1) + (m & 1) * NFREQ;
        const f32x4* src = reinterpret_cast<const f32x4*>(basis + (size_t)br * FL + c);
        f32x4 f0 = src[0], f1 = src[1];
        v[0] = (short)f2bf(f0[0]); v[1] = (short)f2bf(f0[1]);
        v[2] = (short)f2bf(f0[2]); v[3] = (short)f2bf(f0[3]);
        v[4] = (short)f2bf(f1[0]); v[5] = (short)f2bf(f1[1]);
        v[6] = (short)f2bf(f1[2]); v[7] = (short)f2bf(f1[3]);
    }
    *reinterpret_cast<s16x8*>(Abf + (size_t)m * FL + c) = v;
}

// ---- pre-pass 2: signal fp32 -> bf16 with reflect padding (PAD=512 each side).
// ---- grid (257, 32); 8 consecutive samples per thread, guard ch < 65664.
__global__ __launch_bounds__(256) void cvt_x_kernel(
    const float* __restrict__ x, unsigned short* __restrict__ Xbf)
{
    int ch = blockIdx.x * 256 + threadIdx.x;
    if (ch >= PADLEN / 8) return;
    int b = blockIdx.y;
    const float* xb = x + (size_t)b * NSAMP;
    int p0 = ch * 8;
    int s0 = p0 - 512;
    f32x4 f0, f1;
    if (s0 >= 0 && s0 + 8 <= NSAMP) {
        const f32x4* src = reinterpret_cast<const f32x4*>(xb + s0);  // 16B aligned
        f0 = src[0]; f1 = src[1];
    } else {
        float tmp[8];
#pragma unroll
        for (int e = 0; e < 8; ++e) {
            int s = s0 + e;
            if (s < 0) s = -s;
            if (s >= NSAMP) s = 2 * (NSAMP - 1) - s;
            tmp[e] = xb[s];
        }
        f0[0]=tmp[0]; f0[1]=tmp[1]; f0[2]=tmp[2]; f0[3]=tmp[3];
        f1[0]=tmp[4]; f1[1]=tmp[5]; f1[2]=tmp[6]; f1[3]=tmp[7];
    }
    s16x8 v;
    v[0] = (short)f2bf(f0[0]); v[1] = (short)f2bf(f0[1]);
    v[2] = (short)f2bf(f0[2]); v[3] = (short)f2bf(f0[3]);
    v[4] = (short)f2bf(f1[0]); v[5] = (short)f2bf(f1[1]);
    v[6] = (short)f2bf(f1[2]); v[7] = (short)f2bf(f1[3]);
    *reinterpret_cast<s16x8*>(Xbf + (size_t)b * PADLEN + p0) = v;
}

// ---- main GEMM (m97 structure): global_load_lds width-16 staging, XOR-swizzled
// ---- LDS layout (conflict-free b128 reads), 128x128x64 tiles, fused magnitude.
__global__ __launch_bounds__(256) void stft_gemm_kernel(
    const unsigned short* __restrict__ Abf,
    const unsigned short* __restrict__ Xbf,
    float* __restrict__ out)
{
    __shared__ unsigned short As[BM * BK];   // 16 KB, row-major [row][64], no pad
    __shared__ unsigned short Bs[BN * BK];   // 16 KB

    const int tid = threadIdx.x;
    const int mt = blockIdx.x, tt = blockIdx.y, b = blockIdx.z;
    const int wave = tid >> 6, lane = tid & 63;
    const int wm = wave >> 1, wn = wave & 1;
    const int lm = lane & 15, quad = lane >> 4;

    // staging lane mapping: 8 lanes per row, 16 B each; XOR-swizzle on global side
    const int lrow = lane >> 3;          // 0..7 within the wave's 8-row group
    const int lcol = lane & 7;
    const int jsw  = lcol ^ lrow;        // global chunk to fetch into LDS slot lcol

    const unsigned short* __restrict__ Xb = Xbf + (size_t)b * PADLEN;

    f32x4 acc[4][4];
#pragma unroll
    for (int i = 0; i < 4; ++i)
#pragma unroll
        for (int j = 0; j < 4; ++j)
            acc[i][j] = (f32x4)(0.f);

    for (int k0 = 0; k0 < FL; k0 += BK) {
        __syncthreads();
#pragma unroll
        for (int it = 0; it < 4; ++it) {
            const int rbase = wave * 32 + it * 8;    // wave-uniform LDS row base
            const int row = rbase + lrow;            // per-lane row
            const unsigned short* ga =
                Abf + (size_t)(mt * BM + row) * FL + k0 + jsw * 8;
            __builtin_amdgcn_global_load_lds(
                (const __attribute__((address_space(1))) void*)ga,
                (__attribute__((address_space(3))) void*)&As[rbase * BK],
                16, 0, 0);
            int t = tt * BN + row;
            if (t > NFRAMES - 1) t = NFRAMES - 1;    // clamp; bad cols discarded
            const unsigned short* gb = Xb + (size_t)t * 512 + k0 + jsw * 8;
            __builtin_amdgcn_global_load_lds(
                (const __attribute__((address_space(1))) void*)gb,
                (__attribute__((address_space(3))) void*)&Bs[rbase * BK],
                16, 0, 0);
        }
        __syncthreads();
#pragma unroll
        for (int kk = 0; kk < 2; ++kk) {
            s16x8 af[4], bfv[4];
#pragma unroll
            for (int i = 0; i < 4; ++i) {
                int row = wm * 64 + i * 16 + lm;
                int pos = (quad + kk * 4) ^ (row & 7);
                af[i] = *reinterpret_cast<const s16x8*>(&As[row * BK + pos * 8]);
            }
#pragma unroll
            for (int j = 0; j < 4; ++j) {
                int row = wn * 64 + j * 16 + lm;
                int pos = (quad + kk * 4) ^ (row & 7);
                bfv[j] = *reinterpret_cast<const s16x8*>(&Bs[row * BK + pos * 8]);
            }
#pragma unroll
            for (int i = 0; i < 4; ++i)
#pragma unroll
                for (int j = 0; j < 4; ++j)
                    acc[i][j] = __builtin_amdgcn_mfma_f32_16x16x32_bf16(
                        af[i], bfv[j], acc[i][j], 0, 0, 0);
        }
    }

    // epilogue: fused magnitude, coalesced along t
    const size_t ob = (size_t)b * NFREQ * NFRAMES;
#pragma unroll
    for (int i = 0; i < 4; ++i) {
        int mrow = mt * BM + wm * 64 + i * 16 + quad * 4;
        int g0 = mrow >> 1;
#pragma unroll
        for (int j = 0; j < 4; ++j) {
            int t = tt * BN + wn * 64 + j * 16 + lm;
            if (t >= NFRAMES) continue;
            f32x4 v = acc[i][j];
            float m0 = sqrtf(v[0] * v[0] + v[1] * v[1]);
            float m1 = sqrtf(v[2] * v[2] + v[3] * v[3]);
            if (g0 < NFREQ)     out[ob + (size_t)g0 * NFRAMES + t] = m0;
            if (g0 + 1 < NFREQ) out[ob + (size_t)(g0 + 1) * NFRAMES + t] = m1;
        }
    }
}

extern "C" void kernel_launch(void* const* d_in, const int* in_sizes, int n_in,
                              void* d_out, int out_size, void* d_ws, size_t ws_size,
                              hipStream_t stream) {
    const float* x     = (const float*)d_in[0];   // (32, 524288) fp32
    const float* basis = (const float*)d_in[1];   // (1026, 1024) fp32
    float* out = (float*)d_out;                   // (32, 513, 1025) fp32

    unsigned short* Abf = (unsigned short*)d_ws;            // 1152*1024 bf16 = 2.36 MB
    unsigned short* Xbf = Abf + (size_t)MPAD * FL;          // 32*525312 bf16 = 33.6 MB

    cvt_basis_kernel<<<(MPAD * FL / 8) / 256, 256, 0, stream>>>(basis, Abf);
    cvt_x_kernel<<<dim3((PADLEN / 8 + 255) / 256, 32), 256, 0, stream>>>(x, Xbf);
    stft_gemm_kernel<<<dim3(9, 9, 32), 256, 0, stream>>>(Abf, Xbf, out);
}

// Round 3
// 207.270 us; speedup vs baseline: 2.5080x; 1.0634x over previous
//
#include <hip/hip_runtime.h>
#include <math.h>

typedef short s16x8 __attribute__((ext_vector_type(8)));
typedef float f32x4 __attribute__((ext_vector_type(4)));

#define NSAMP   524288
#define NFRAMES 1025
#define NTOT    32800      // 32 * 1025 frames
#define KF      512        // folded K
#define BM      128
#define BN      128
#define BK      64
#define OUTB    525825     // 513*1025 per batch

__device__ __forceinline__ unsigned short f2bf(float f) {
    unsigned u = __float_as_uint(f);
    u += 0x7fffu + ((u >> 16) & 1u);
    return (unsigned short)(u >> 16);
}
__device__ __forceinline__ float bf2f(unsigned short h) {
    return __uint_as_float(((unsigned)h) << 16);
}

// ---- prep A: Are[f][n]=basis[f][n], Aim[f][n]=basis[513+f][n], f,n in [0,512) ----
__global__ __launch_bounds__(256) void prep_A(
    const float* __restrict__ basis,
    unsigned short* __restrict__ Are, unsigned short* __restrict__ Aim)
{
    int gid = blockIdx.x * 256 + threadIdx.x;     // 65536 total
    int sel = gid >> 15;
    int idx = gid & 32767;
    int f = idx >> 6;
    int c = (idx & 63) * 8;
    const float* src = basis + (size_t)(sel ? 513 + f : f) * 1024 + c;
    f32x4 a = *reinterpret_cast<const f32x4*>(src);
    f32x4 b = *reinterpret_cast<const f32x4*>(src + 4);
    s16x8 v;
    v[0]=(short)f2bf(a[0]); v[1]=(short)f2bf(a[1]); v[2]=(short)f2bf(a[2]); v[3]=(short)f2bf(a[3]);
    v[4]=(short)f2bf(b[0]); v[5]=(short)f2bf(b[1]); v[6]=(short)f2bf(b[2]); v[7]=(short)f2bf(b[3]);
    unsigned short* dst = sel ? Aim : Are;
    *reinterpret_cast<s16x8*>(dst + (size_t)f * KF + c) = v;
}

// ---- fold: Y+[gt][n] = x~(n) + x~(1024-n), Y-[gt][n] = x~(n) - x~(1024-n), n=1..511
// ---- slot 0 = 0 (its basis coeff is exactly 0 since w[0]=0). One wave per frame.
__global__ __launch_bounds__(256) void fold_kernel(
    const float* __restrict__ x,
    unsigned short* __restrict__ Yp, unsigned short* __restrict__ Ym)
{
    int gt = blockIdx.x * 4 + (threadIdx.x >> 6);
    if (gt >= NTOT) return;
    int lane = threadIdx.x & 63;
    int b = gt / 1025, t = gt - b * 1025;
    const float* __restrict__ xb = x + (size_t)b * NSAMP;
    int n0 = lane * 8;
    int base = t * 512;
    float vp[8], vm[8];
    int s1 = base + n0 - 512;           // ascending, 16B aligned
    int s2lo = base + 512 - n0 - 7;     // ascending, maps to n = n0+7 .. n0
    if (n0 > 0 && s1 >= 0 && (base + 512 - n0) < NSAMP) {
        f32x4 a0 = *reinterpret_cast<const f32x4*>(xb + s1);
        f32x4 a1 = *reinterpret_cast<const f32x4*>(xb + s1 + 4);
        float v2[8];
        __builtin_memcpy(v2, xb + s2lo, 32);    // unaligned ok
        float v1[8] = {a0[0],a0[1],a0[2],a0[3],a1[0],a1[1],a1[2],a1[3]};
#pragma unroll
        for (int e = 0; e < 8; ++e) {
            float xa = v1[e], xbv = v2[7 - e];
            vp[e] = xa + xbv; vm[e] = xa - xbv;
        }
    } else {
#pragma unroll
        for (int e = 0; e < 8; ++e) {
            int n = n0 + e;
            if (n == 0) { vp[e] = 0.f; vm[e] = 0.f; continue; }
            int sa = base + n - 512;
            if (sa < 0) sa = -sa;                       // never >= NSAMP
            int sb = base + 512 - n;                    // never < 0
            if (sb >= NSAMP) sb = 2 * (NSAMP - 1) - sb;
            float xa = xb[sa], xbv = xb[sb];
            vp[e] = xa + xbv; vm[e] = xa - xbv;
        }
    }
    s16x8 wp, wm;
#pragma unroll
    for (int e = 0; e < 8; ++e) { wp[e] = (short)f2bf(vp[e]); wm[e] = (short)f2bf(vm[e]); }
    *reinterpret_cast<s16x8*>(Yp + (size_t)gt * KF + n0) = wp;
    *reinterpret_cast<s16x8*>(Ym + (size_t)gt * KF + n0) = wm;
}

// ---- main GEMM: M=512 (f 0..511), N = all 32800 frames tiled by 128, two K=512
// ---- phases (re, im) into separate accs; fused magnitude + center term.
__global__ __launch_bounds__(256, 2) void stft_gemm(
    const unsigned short* __restrict__ Are, const unsigned short* __restrict__ Aim,
    const unsigned short* __restrict__ Yp,  const unsigned short* __restrict__ Ym,
    const float* __restrict__ x, float* __restrict__ out)
{
    __shared__ unsigned short As[BM * BK];
    __shared__ unsigned short Bs[BN * BK];

    // XCD-aware swizzle: same nt stays on one XCD (round-robin assumption)
    int id = blockIdx.x;
    int nt = (id & 7) + 8 * (id >> 5);
    int mt = (id >> 3) & 3;
    if (nt >= 257) return;

    const int tid = threadIdx.x;
    const int wave = tid >> 6, lane = tid & 63;
    const int wm = wave >> 1, wn = wave & 1;
    const int lm = lane & 15, quad = lane >> 4;
    const int lrow = lane >> 3, lcol = lane & 7;
    const int jsw = lcol ^ lrow;

    f32x4 accre[4][4], accim[4][4];
#pragma unroll
    for (int i = 0; i < 4; ++i)
#pragma unroll
        for (int j = 0; j < 4; ++j) { accre[i][j] = (f32x4)(0.f); accim[i][j] = (f32x4)(0.f); }

    auto phase = [&](const unsigned short* __restrict__ A,
                     const unsigned short* __restrict__ B,
                     f32x4 (&acc)[4][4]) {
        for (int k0 = 0; k0 < KF; k0 += BK) {
            __syncthreads();
#pragma unroll
            for (int it = 0; it < 4; ++it) {
                const int rbase = wave * 32 + it * 8;
                const int row = rbase + lrow;
                const unsigned short* ga = A + (size_t)(mt * BM + row) * KF + k0 + jsw * 8;
                __builtin_amdgcn_global_load_lds(
                    (const __attribute__((address_space(1))) void*)ga,
                    (__attribute__((address_space(3))) void*)&As[rbase * BK], 16, 0, 0);
                int gtb = nt * BN + row;
                if (gtb > NTOT - 1) gtb = NTOT - 1;
                const unsigned short* gb = B + (size_t)gtb * KF + k0 + jsw * 8;
                __builtin_amdgcn_global_load_lds(
                    (const __attribute__((address_space(1))) void*)gb,
                    (__attribute__((address_space(3))) void*)&Bs[rbase * BK], 16, 0, 0);
            }
            __syncthreads();
#pragma unroll
            for (int kk = 0; kk < 2; ++kk) {
                s16x8 af[4], bfv[4];
#pragma unroll
                for (int i = 0; i < 4; ++i) {
                    int row = wm * 64 + i * 16 + lm;
                    int pos = (quad + kk * 4) ^ (row & 7);
                    af[i] = *reinterpret_cast<const s16x8*>(&As[row * BK + pos * 8]);
                }
#pragma unroll
                for (int j = 0; j < 4; ++j) {
                    int row = wn * 64 + j * 16 + lm;
                    int pos = (quad + kk * 4) ^ (row & 7);
                    bfv[j] = *reinterpret_cast<const s16x8*>(&Bs[row * BK + pos * 8]);
                }
#pragma unroll
                for (int i = 0; i < 4; ++i)
#pragma unroll
                    for (int j = 0; j < 4; ++j)
                        acc[i][j] = __builtin_amdgcn_mfma_f32_16x16x32_bf16(
                            af[i], bfv[j], acc[i][j], 0, 0, 0);
            }
        }
    };

    phase(Are, Yp, accre);
    phase(Aim, Ym, accim);

    // epilogue: re += (-1)^f * x_center(t); magnitude; store
#pragma unroll
    for (int j = 0; j < 4; ++j) {
        int gtj = nt * BN + wn * 64 + j * 16 + lm;
        if (gtj >= NTOT) continue;
        int bj = gtj / 1025, tj = gtj - bj * 1025;
        int sc = tj * 512;
        if (sc >= NSAMP) sc = NSAMP - 2;
        float xc = x[(size_t)bj * NSAMP + sc];
        size_t obase = (size_t)bj * OUTB + tj;
#pragma unroll
        for (int i = 0; i < 4; ++i) {
            int f0 = mt * BM + wm * 64 + i * 16 + quad * 4;   // even
            f32x4 vr = accre[i][j], vi = accim[i][j];
#pragma unroll
            for (int r = 0; r < 4; ++r) {
                float re = vr[r] + ((r & 1) ? -xc : xc);
                float im = vi[r];
                out[obase + (size_t)(f0 + r) * 1025] = sqrtf(re * re + im * im);
            }
        }
    }
}

// ---- Nyquist row f=512: |sum_n basis[512][n]*Y+[gt][n] + x_center| ----
__global__ __launch_bounds__(256) void nyq_kernel(
    const unsigned short* __restrict__ Yp, const float* __restrict__ basis,
    const float* __restrict__ x, float* __restrict__ out)
{
    int gt = blockIdx.x * 4 + (threadIdx.x >> 6);
    if (gt >= NTOT) return;
    int lane = threadIdx.x & 63;
    s16x8 v = *reinterpret_cast<const s16x8*>(Yp + (size_t)gt * KF + lane * 8);
    const float* c = basis + 512 * 1024 + lane * 8;
    float s = 0.f;
#pragma unroll
    for (int e = 0; e < 8; ++e) s += bf2f((unsigned short)v[e]) * c[e];
#pragma unroll
    for (int off = 32; off > 0; off >>= 1) s += __shfl_xor(s, off, 64);
    if (lane == 0) {
        int b = gt / 1025, t = gt - b * 1025;
        int sc = t * 512;
        if (sc >= NSAMP) sc = NSAMP - 2;
        float val = s + x[(size_t)b * NSAMP + sc];
        out[(size_t)b * OUTB + 512 * 1025 + t] = fabsf(val);
    }
}

extern "C" void kernel_launch(void* const* d_in, const int* in_sizes, int n_in,
                              void* d_out, int out_size, void* d_ws, size_t ws_size,
                              hipStream_t stream) {
    const float* x     = (const float*)d_in[0];   // (32, 524288) fp32
    const float* basis = (const float*)d_in[1];   // (1026, 1024) fp32
    float* out = (float*)d_out;                   // (32, 513, 1025) fp32

    unsigned short* Are = (unsigned short*)d_ws;                          // 512 KB
    unsigned short* Aim = Are + (size_t)512 * KF;                         // 512 KB
    unsigned short* Yp  = (unsigned short*)((char*)d_ws + (1 << 20));     // 33.6 MB
    unsigned short* Ym  = Yp + (size_t)NTOT * KF;                         // 33.6 MB

    prep_A<<<256, 256, 0, stream>>>(basis, Are, Aim);
    fold_kernel<<<8200, 256, 0, stream>>>(x, Yp, Ym);
    stft_gemm<<<1056, 256, 0, stream>>>(Are, Aim, Yp, Ym, x, out);
    nyq_kernel<<<8200, 256, 0, stream>>>(Yp, basis, x, out);
}

// Round 4
// 158.877 us; speedup vs baseline: 3.2719x; 1.3046x over previous
//
#include <hip/hip_runtime.h>
#include <math.h>

#define NSAMP 524288
#define NTOT  32800      // 32 * 1025 frames
#define OUTB  525825     // 513*1025 per batch
#define FPB   16         // frames per block

// 8-point complex forward DFT, natural order in/out, in registers.
__device__ __forceinline__ void fft8(float (&xr)[8], float (&xi)[8]) {
    const float S2 = 0.70710678118654752f;
    // evens c0,c2,c4,c6 -> E
    float t0r = xr[0] + xr[4], t0i = xi[0] + xi[4];
    float t1r = xr[0] - xr[4], t1i = xi[0] - xi[4];
    float t2r = xr[2] + xr[6], t2i = xi[2] + xi[6];
    float t3r = xr[2] - xr[6], t3i = xi[2] - xi[6];
    float E0r = t0r + t2r, E0i = t0i + t2i;
    float E2r = t0r - t2r, E2i = t0i - t2i;
    float E1r = t1r + t3i, E1i = t1i - t3r;   // t1 - i*t3
    float E3r = t1r - t3i, E3i = t1i + t3r;   // t1 + i*t3
    // odds c1,c3,c5,c7 -> O
    float u0r = xr[1] + xr[5], u0i = xi[1] + xi[5];
    float u1r = xr[1] - xr[5], u1i = xi[1] - xi[5];
    float u2r = xr[3] + xr[7], u2i = xi[3] + xi[7];
    float u3r = xr[3] - xr[7], u3i = xi[3] - xi[7];
    float O0r = u0r + u2r, O0i = u0i + u2i;
    float O2r = u0r - u2r, O2i = u0i - u2i;
    float O1r = u1r + u3i, O1i = u1i - u3r;
    float O3r = u1r - u3i, O3i = u1i + u3r;
    // O1 *= s(1-i); O2 *= -i; O3 *= -s(1+i)
    float w1r = S2 * (O1r + O1i), w1i = S2 * (O1i - O1r);
    float w2r = O2i,              w2i = -O2r;
    float w3r = S2 * (O3i - O3r), w3i = -S2 * (O3r + O3i);
    xr[0] = E0r + O0r; xi[0] = E0i + O0i;
    xr[4] = E0r - O0r; xi[4] = E0i - O0i;
    xr[1] = E1r + w1r; xi[1] = E1i + w1i;
    xr[5] = E1r - w1r; xi[5] = E1i - w1i;
    xr[2] = E2r + w2r; xi[2] = E2i + w2i;
    xr[6] = E2r - w2r; xi[6] = E2i - w2i;
    xr[3] = E3r + w3r; xi[3] = E3i + w3i;
    xr[7] = E3r - w3r; xi[7] = E3i - w3i;
}

// One wave per frame; 512-pt complex FFT as 8(reg) x 8(reg) x 8(reg) with two
// intra-wave LDS transposes (stride-72 planes: all patterns <=2-way banked).
// Real-input via even/odd complex packing + unpack. Magnitude fused. 16 frames
// staged in obuf (stride 17, 2-way) then written as 64B-coalesced row segments.
__global__ __launch_bounds__(256) void stft_fft_kernel(
    const float* __restrict__ x, float* __restrict__ out)
{
    __shared__ float scr[4][1184];      // per-wave: re plane [0,1152) split 576/576
    __shared__ float obuf[513 * 17];    // [freq][frame-slot], stride 17

    const int tid = threadIdx.x;
    const int wave = tid >> 6, l = tid & 63;
    float* S = scr[wave];
    const int gt0 = blockIdx.x * FPB;
    const float PI = 3.14159265358979f;

    for (int it = 0; it < 4; ++it) {
        const int tloc = wave * 4 + it;
        const int gt = gt0 + tloc;
        const int b = gt / 1025;
        const int t = gt - b * 1025;
        const float* __restrict__ xb = x + (size_t)b * NSAMP;
        const int sbase = t * 512 - 512;

        float cr[8], ci[8];
        float c1, s1;                       // theta0 = pi*l/256 (window & T1 twiddle)
        __sincosf(PI * (float)l * (1.0f / 256.0f), &s1, &c1);

        asm volatile("s_waitcnt lgkmcnt(0)" ::: "memory");  // prev-frame scratch reads done

        // ---- load + Hann window; z[m]=xw[2m]+i*xw[2m+1], m = l + 64*n1 ----
        {
            float cs = c1, sn = s1;
            const float CD = 0.9999811753f, SD = 0.0061358846f; // 2pi/1024
            const float C4 = 0.70710678f;                       // pi/4 step
            const bool edge = (t == 0) || (t == 1024);
#pragma unroll
            for (int n1 = 0; n1 < 8; ++n1) {
                const int n = 2 * (l + 64 * n1);
                float xe, xo;
                if (!edge) {
                    const float2 v = *reinterpret_cast<const float2*>(xb + sbase + n);
                    xe = v.x; xo = v.y;
                } else {
                    int sa = sbase + n, sb2 = sbase + n + 1;
                    if (sa < 0) sa = -sa;
                    if (sa >= NSAMP) sa = 2 * (NSAMP - 1) - sa;
                    if (sb2 < 0) sb2 = -sb2;
                    if (sb2 >= NSAMP) sb2 = 2 * (NSAMP - 1) - sb2;
                    xe = xb[sa]; xo = xb[sb2];
                }
                const float we = 0.5f - 0.5f * cs;              // w[2m]
                const float cso = cs * CD - sn * SD;
                const float wo = 0.5f - 0.5f * cso;             // w[2m+1]
                cr[n1] = xe * we;
                ci[n1] = xo * wo;
                const float cn = cs * C4 - sn * C4;             // advance pi/4
                sn = sn * C4 + cs * C4;
                cs = cn;
            }
        }

        fft8(cr, ci);   // over n1 -> reg index kappa = k mod 8

        // ---- twiddle e^{-2pi i * l * kappa / 512} = (c1,-s1)^kappa ----
        {
            float wr = c1, wi = -s1;
#pragma unroll
            for (int k = 1; k < 8; ++k) {
                const float rr = cr[k] * wr - ci[k] * wi;
                const float ii = cr[k] * wi + ci[k] * wr;
                cr[k] = rr; ci[k] = ii;
                const float nwr = wr * c1 + wi * s1;
                const float nwi = wi * c1 - wr * s1;
                wr = nwr; wi = nwi;
            }
        }

        // ---- transpose 1: lane n2=l reg kappa  ->  lane (kappa,m2) reg m1 ----
#pragma unroll
        for (int k = 0; k < 8; ++k) { S[k * 72 + l] = cr[k]; S[576 + k * 72 + l] = ci[k]; }
        asm volatile("s_waitcnt lgkmcnt(0)" ::: "memory");
        const int kap = l >> 3, m2 = l & 7;
#pragma unroll
        for (int m1 = 0; m1 < 8; ++m1) {
            cr[m1] = S[kap * 72 + 8 * m1 + m2];
            ci[m1] = S[576 + kap * 72 + 8 * m1 + m2];
        }
        asm volatile("s_waitcnt lgkmcnt(0)" ::: "memory");

        fft8(cr, ci);   // over m1 -> reg index j1

        // ---- twiddle e^{-2pi i * m2 * j1 / 64} ----
        {
            float cb, sb;
            __sincosf(PI * (float)m2 * (1.0f / 32.0f), &sb, &cb);
            float wr = cb, wi = -sb;
#pragma unroll
            for (int j = 1; j < 8; ++j) {
                const float rr = cr[j] * wr - ci[j] * wi;
                const float ii = cr[j] * wi + ci[j] * wr;
                cr[j] = rr; ci[j] = ii;
                const float nwr = wr * cb + wi * sb;
                const float nwi = wi * cb - wr * sb;
                wr = nwr; wi = nwi;
            }
        }

        // ---- transpose 2 (within kappa-group): reg j1 <-> lane m2 ----
#pragma unroll
        for (int j = 0; j < 8; ++j) {
            S[j * 72 + 8 * m2 + kap] = cr[j];
            S[576 + j * 72 + 8 * m2 + kap] = ci[j];
        }
        asm volatile("s_waitcnt lgkmcnt(0)" ::: "memory");
        const int j1 = l & 7;   // lane is now (kap, j1)
#pragma unroll
        for (int m = 0; m < 8; ++m) {
            cr[m] = S[j1 * 72 + 8 * m + kap];
            ci[m] = S[576 + j1 * 72 + 8 * m + kap];
        }
        asm volatile("s_waitcnt lgkmcnt(0)" ::: "memory");

        fft8(cr, ci);   // over m2 -> reg index j2:  Z[kap + 8*j1 + 64*j2]

        // ---- store Z to LDS (k-indexed planes) ----
#pragma unroll
        for (int j2 = 0; j2 < 8; ++j2) {
            const int k = kap + 8 * j1 + 64 * j2;
            S[k] = cr[j2]; S[576 + k] = ci[j2];
        }
        asm volatile("s_waitcnt lgkmcnt(0)" ::: "memory");

        // ---- real-FFT unpack + magnitude: k = l + 64r ----
        {
            float cbb, sbb;
            __sincosf(PI * (float)l * (1.0f / 512.0f), &sbb, &cbb);
            float wr = cbb, wi = -sbb;                          // e^{-2pi i k/1024}
            const float CS8 = 0.9238795325f, SN8 = 0.3826834324f; // pi/8 step
#pragma unroll
            for (int r = 0; r < 8; ++r) {
                const int k = l + 64 * r;
                const int k2 = (512 - k) & 511;
                const float Zer = S[k],  Zei = S[576 + k];
                const float Zor = S[k2], Zoi = S[576 + k2];
                const float Ar = 0.5f * (Zer + Zor);
                const float Ai = 0.5f * (Zei - Zoi);
                const float Br = 0.5f * (Zei + Zoi);
                const float Bi = 0.5f * (Zor - Zer);
                const float Xr = Ar + Br * wr - Bi * wi;
                const float Xi = Ai + Br * wi + Bi * wr;
                obuf[k * 17 + tloc] = sqrtf(Xr * Xr + Xi * Xi);
                const float nwr = wr * CS8 + wi * SN8;
                const float nwi = wi * CS8 - wr * SN8;
                wr = nwr; wi = nwi;
            }
            if (l == 0) obuf[512 * 17 + tloc] = fabsf(S[0] - S[576]);  // Nyquist
        }
    }

    __syncthreads();

    // ---- cooperative write-out: 16 rows x 16 t-columns per pass (64B segments) ----
    const int kk = tid >> 4, c = tid & 15;
    const int gtc = gt0 + c;
    const int bc = gtc / 1025, tc = gtc - bc * 1025;
    const size_t oaddr = (size_t)bc * OUTB + tc;
#pragma unroll
    for (int p = 0; p < 33; ++p) {
        const int k = p * 16 + kk;
        if (k < 513) out[oaddr + (size_t)k * 1025] = obuf[k * 17 + c];
    }
}

extern "C" void kernel_launch(void* const* d_in, const int* in_sizes, int n_in,
                              void* d_out, int out_size, void* d_ws, size_t ws_size,
                              hipStream_t stream) {
    const float* x = (const float*)d_in[0];   // (32, 524288) fp32
    float* out = (float*)d_out;               // (32, 513, 1025) fp32
    stft_fft_kernel<<<NTOT / FPB, 256, 0, stream>>>(x, out);
}

// Round 5
// 155.822 us; speedup vs baseline: 3.3361x; 1.0196x over previous
//
#include <hip/hip_runtime.h>
#include <math.h>

#define NSAMP 524288
#define NTOT  32800      // 32 * 1025 frames
#define OUTB  525825     // 513*1025 per batch
#define FPB   16         // frames per block

// 8-point complex forward DFT, natural order in/out, in registers.
__device__ __forceinline__ void fft8(float (&xr)[8], float (&xi)[8]) {
    const float S2 = 0.70710678118654752f;
    float t0r = xr[0] + xr[4], t0i = xi[0] + xi[4];
    float t1r = xr[0] - xr[4], t1i = xi[0] - xi[4];
    float t2r = xr[2] + xr[6], t2i = xi[2] + xi[6];
    float t3r = xr[2] - xr[6], t3i = xi[2] - xi[6];
    float E0r = t0r + t2r, E0i = t0i + t2i;
    float E2r = t0r - t2r, E2i = t0i - t2i;
    float E1r = t1r + t3i, E1i = t1i - t3r;
    float E3r = t1r - t3i, E3i = t1i + t3r;
    float u0r = xr[1] + xr[5], u0i = xi[1] + xi[5];
    float u1r = xr[1] - xr[5], u1i = xi[1] - xi[5];
    float u2r = xr[3] + xr[7], u2i = xi[3] + xi[7];
    float u3r = xr[3] - xr[7], u3i = xi[3] - xi[7];
    float O0r = u0r + u2r, O0i = u0i + u2i;
    float O2r = u0r - u2r, O2i = u0i - u2i;
    float O1r = u1r + u3i, O1i = u1i - u3r;
    float O3r = u1r - u3i, O3i = u1i + u3r;
    float w1r = S2 * (O1r + O1i), w1i = S2 * (O1i - O1r);
    float w2r = O2i,              w2i = -O2r;
    float w3r = S2 * (O3i - O3r), w3i = -S2 * (O3r + O3i);
    xr[0] = E0r + O0r; xi[0] = E0i + O0i;
    xr[4] = E0r - O0r; xi[4] = E0i - O0i;
    xr[1] = E1r + w1r; xi[1] = E1i + w1i;
    xr[5] = E1r - w1r; xi[5] = E1i - w1i;
    xr[2] = E2r + w2r; xi[2] = E2i + w2i;
    xr[6] = E2r - w2r; xi[6] = E2i - w2i;
    xr[3] = E3r + w3r; xi[3] = E3i + w3i;
    xr[7] = E3r - w3r; xi[7] = E3i - w3i;
}

// One wave handles 4 frames as 2 iterations x 2 interleaved frames (ILP pair).
// 512-pt complex FFT = 8(reg) x 8(reg) x 8(reg), two intra-wave LDS transposes.
// All twiddles/window coeffs hoisted (loop-invariant per lane). No manual
// waitcnt drains: DS ops within a wave complete in order; compiler inserts
// fine-grained lgkm waits before register use.
__global__ __launch_bounds__(256, 2) void stft_fft_kernel(
    const float* __restrict__ x, float* __restrict__ out)
{
    __shared__ float scr[4][2][1184];   // per-wave, per-stream plane: re[576]+im[576]
    __shared__ float obuf[513 * 17];    // [freq][frame-slot], stride 17

    const int tid = threadIdx.x;
    const int wave = tid >> 6, l = tid & 63;
    const int kap = l >> 3, m2 = l & 7, j1 = l & 7;
    const int gt0 = blockIdx.x * FPB;
    const float PI = 3.14159265358979f;

    // ================= hoisted per-lane constants =================
    float c1, s1;                        // e^{i pi l/256}
    __sincosf(PI * (float)l * (1.0f / 256.0f), &s1, &c1);

    // window coeffs for n = 2(l+64 n1) and +1
    float wea[8], woa[8];
    {
        const float CD = 0.9999811753f, SD = 0.0061358846f;  // 2pi/1024
        const float C4 = 0.70710678f;                        // pi/4 step
        float cs = c1, sn = s1;
#pragma unroll
        for (int n1 = 0; n1 < 8; ++n1) {
            wea[n1] = 0.5f - 0.5f * cs;
            const float cso = cs * CD - sn * SD;
            woa[n1] = 0.5f - 0.5f * cso;
            const float cn = cs * C4 - sn * C4;
            sn = sn * C4 + cs * C4;
            cs = cn;
        }
    }
    // T1 twiddles: (c1 - i s1)^k, k=1..7
    float w1r[8], w1i[8];
    {
        float wr = c1, wi = -s1;
#pragma unroll
        for (int k = 1; k < 8; ++k) {
            w1r[k] = wr; w1i[k] = wi;
            const float nwr = wr * c1 + wi * s1;
            const float nwi = wi * c1 - wr * s1;
            wr = nwr; wi = nwi;
        }
    }
    // T2 twiddles: e^{-2pi i m2 j/64}, j=1..7
    float w2r[8], w2i[8];
    {
        float cb, sb;
        __sincosf(PI * (float)m2 * (1.0f / 32.0f), &sb, &cb);
        float wr = cb, wi = -sb;
#pragma unroll
        for (int j = 1; j < 8; ++j) {
            w2r[j] = wr; w2i[j] = wi;
            const float nwr = wr * cb + wi * sb;
            const float nwi = wi * cb - wr * sb;
            wr = nwr; wi = nwi;
        }
    }
    // unpack twiddles: e^{-2pi i (l+64r)/1024}, r=0..7
    float w3r[8], w3i[8];
    {
        float cbb, sbb;
        __sincosf(PI * (float)l * (1.0f / 512.0f), &sbb, &cbb);
        const float CS8 = 0.9238795325f, SN8 = 0.3826834324f;  // pi/8
        float wr = cbb, wi = -sbb;
#pragma unroll
        for (int r = 0; r < 8; ++r) {
            w3r[r] = wr; w3i[r] = wi;
            const float nwr = wr * CS8 + wi * SN8;
            const float nwi = wi * CS8 - wr * SN8;
            wr = nwr; wi = nwi;
        }
    }
    // ==============================================================

    for (int it = 0; it < 2; ++it) {
        float cr[2][8], ci[2][8];
        int tl[2]; const float* xbp[2]; int sb0[2]; bool edge[2];
#pragma unroll
        for (int p = 0; p < 2; ++p) {
            const int tloc = wave * 4 + it * 2 + p;
            const int gt = gt0 + tloc;
            const int b = gt / 1025;
            const int t = gt - b * 1025;
            tl[p] = tloc;
            xbp[p] = x + (size_t)b * NSAMP;
            sb0[p] = t * 512 - 512;
            edge[p] = (t == 0) || (t == 1024);
        }

        // ---- load both streams (16 loads in flight), then window ----
#pragma unroll
        for (int p = 0; p < 2; ++p) {
            if (!edge[p]) {
#pragma unroll
                for (int n1 = 0; n1 < 8; ++n1) {
                    const float2 v = *reinterpret_cast<const float2*>(
                        xbp[p] + sb0[p] + 2 * (l + 64 * n1));
                    cr[p][n1] = v.x; ci[p][n1] = v.y;
                }
            } else {
#pragma unroll
                for (int n1 = 0; n1 < 8; ++n1) {
                    const int n = 2 * (l + 64 * n1);
                    int sa = sb0[p] + n, sb2 = sb0[p] + n + 1;
                    if (sa < 0) sa = -sa;
                    if (sa >= NSAMP) sa = 2 * (NSAMP - 1) - sa;
                    if (sb2 < 0) sb2 = -sb2;
                    if (sb2 >= NSAMP) sb2 = 2 * (NSAMP - 1) - sb2;
                    cr[p][n1] = xbp[p][sa]; ci[p][n1] = xbp[p][sb2];
                }
            }
        }
#pragma unroll
        for (int p = 0; p < 2; ++p)
#pragma unroll
            for (int n1 = 0; n1 < 8; ++n1) {
                cr[p][n1] *= wea[n1]; ci[p][n1] *= woa[n1];
            }

        fft8(cr[0], ci[0]); fft8(cr[1], ci[1]);

        // twiddle 1
#pragma unroll
        for (int p = 0; p < 2; ++p)
#pragma unroll
            for (int k = 1; k < 8; ++k) {
                const float rr = cr[p][k] * w1r[k] - ci[p][k] * w1i[k];
                const float ii = cr[p][k] * w1i[k] + ci[p][k] * w1r[k];
                cr[p][k] = rr; ci[p][k] = ii;
            }

        // transpose 1
#pragma unroll
        for (int p = 0; p < 2; ++p) {
            float* P = scr[wave][p];
#pragma unroll
            for (int k = 0; k < 8; ++k) {
                P[k * 72 + l] = cr[p][k];
                P[576 + k * 72 + l] = ci[p][k];
            }
        }
#pragma unroll
        for (int p = 0; p < 2; ++p) {
            float* P = scr[wave][p];
#pragma unroll
            for (int m1 = 0; m1 < 8; ++m1) {
                cr[p][m1] = P[kap * 72 + 8 * m1 + m2];
                ci[p][m1] = P[576 + kap * 72 + 8 * m1 + m2];
            }
        }

        fft8(cr[0], ci[0]); fft8(cr[1], ci[1]);

        // twiddle 2
#pragma unroll
        for (int p = 0; p < 2; ++p)
#pragma unroll
            for (int j = 1; j < 8; ++j) {
                const float rr = cr[p][j] * w2r[j] - ci[p][j] * w2i[j];
                const float ii = cr[p][j] * w2i[j] + ci[p][j] * w2r[j];
                cr[p][j] = rr; ci[p][j] = ii;
            }

        // transpose 2 (within kappa-group)
#pragma unroll
        for (int p = 0; p < 2; ++p) {
            float* P = scr[wave][p];
#pragma unroll
            for (int j = 0; j < 8; ++j) {
                P[j * 72 + 8 * m2 + kap] = cr[p][j];
                P[576 + j * 72 + 8 * m2 + kap] = ci[p][j];
            }
        }
#pragma unroll
        for (int p = 0; p < 2; ++p) {
            float* P = scr[wave][p];
#pragma unroll
            for (int m = 0; m < 8; ++m) {
                cr[p][m] = P[j1 * 72 + 8 * m + kap];
                ci[p][m] = P[576 + j1 * 72 + 8 * m + kap];
            }
        }

        fft8(cr[0], ci[0]); fft8(cr[1], ci[1]);   // Z[kap + 8*j1 + 64*j2]

        // Z store (k-indexed) + real-FFT unpack + magnitude
#pragma unroll
        for (int p = 0; p < 2; ++p) {
            float* P = scr[wave][p];
#pragma unroll
            for (int j2 = 0; j2 < 8; ++j2) {
                const int k = kap + 8 * j1 + 64 * j2;
                P[k] = cr[p][j2]; P[576 + k] = ci[p][j2];
            }
        }
#pragma unroll
        for (int p = 0; p < 2; ++p) {
            float* P = scr[wave][p];
#pragma unroll
            for (int r = 0; r < 8; ++r) {
                const int k = l + 64 * r;
                const int k2 = (512 - k) & 511;
                const float Zer = P[k],  Zei = P[576 + k];
                const float Zor = P[k2], Zoi = P[576 + k2];
                const float Ar = 0.5f * (Zer + Zor);
                const float Ai = 0.5f * (Zei - Zoi);
                const float Br = 0.5f * (Zei + Zoi);
                const float Bi = 0.5f * (Zor - Zer);
                const float Xr = Ar + Br * w3r[r] - Bi * w3i[r];
                const float Xi = Ai + Br * w3i[r] + Bi * w3r[r];
                obuf[k * 17 + tl[p]] = sqrtf(Xr * Xr + Xi * Xi);
            }
            if (l == 0) obuf[512 * 17 + tl[p]] = fabsf(P[0] - P[576]);  // Nyquist
        }
    }

    __syncthreads();

    // ---- cooperative write-out: 16 rows x 16 t-columns per pass (64B segments) ----
    const int kk = tid >> 4, c = tid & 15;
    const int gtc = gt0 + c;
    const int bc = gtc / 1025, tc = gtc - bc * 1025;
    const size_t oaddr = (size_t)bc * OUTB + tc;
#pragma unroll
    for (int p = 0; p < 33; ++p) {
        const int k = p * 16 + kk;
        if (k < 513) out[oaddr + (size_t)k * 1025] = obuf[k * 17 + c];
    }
}

extern "C" void kernel_launch(void* const* d_in, const int* in_sizes, int n_in,
                              void* d_out, int out_size, void* d_ws, size_t ws_size,
                              hipStream_t stream) {
    const float* x = (const float*)d_in[0];   // (32, 524288) fp32
    float* out = (float*)d_out;               // (32, 513, 1025) fp32
    stft_fft_kernel<<<NTOT / FPB, 256, 0, stream>>>(x, out);
}